// Round 8
// baseline (557.402 us; speedup 1.0000x reference)
//
#include <hip/hip_runtime.h>
#include <math.h>

// OnlineLabelSmoothing: B=16384 rows, C=4096 classes, f32.
// out = [loss(1), update(C*C), idx_count(C)] f32.
// Round 8: persistent waves (1024 blocks x 4 waves = 4096 waves = exact
// residency at 4 waves/SIMD), each wave owns 4 CONTIGUOUS rows, and the
// PF=4 prefetch ring carries ACROSS row boundaries: while the wave does
// row r's shuffle-reduce, row r+1's first chunks are already in flight.
// (r3-r7 plateaued ~2 TB/s: per-row latency bubble + reduce with VMEM
// idle + wave retire = ~40% memory duty. This removes the bubbles.)

constexpr int CC   = 4096;
constexpr int WAVE = 64;
constexpr int WPB  = 4;              // waves per block
constexpr int TPB  = WAVE * WPB;     // 256
constexpr int K16  = CC / (WAVE * 4);// 16 float4 chunks per lane per row
constexpr int PF   = 4;              // prefetch ring depth (pow2)
constexpr int BLOCKS_MAIN = 1024;    // 4096 waves total
constexpr float ALPHA_V = 0.5f;
constexpr int ACC_SLOTS = 64;        // loss accumulator spread (x2 doubles)

__device__ inline void amax2(float v, int i, float& bv, int& bi) {
  // first-occurrence argmax: prefer smaller index on exact tie
  if (v > bv || (v == bv && i < bi)) { bv = v; bi = i; }
}

__device__ inline void wave_argmax(float& lv, int& li) {
  #pragma unroll
  for (int o = 1; o < WAVE; o <<= 1) {
    float ov = __shfl_xor(lv, o, WAVE);
    int   oi = __shfl_xor(li, o, WAVE);
    amax2(ov, oi, lv, li);
  }
}

__device__ inline float wave_sum(float v) {
  #pragma unroll
  for (int o = 1; o < WAVE; o <<= 1) v += __shfl_xor(v, o, WAVE);
  return v;
}

// ---- supervise transpose + ALL zeroing fused ----
__global__ void ols_transpose(const float* __restrict__ in,
                              float* __restrict__ supT,
                              float* __restrict__ upd,
                              float* __restrict__ out0,
                              float* __restrict__ cnt,
                              double* __restrict__ acc, int C) {
  __shared__ float tile[32][33];
  const int bx = blockIdx.x * 32, by = blockIdx.y * 32;
  const int tx = threadIdx.x, ty = threadIdx.y;  // (32, 8)
  // fused zeroing of small outputs (parallel across row-0 blocks)
  if (blockIdx.y == 0 && ty == 0) cnt[bx + tx] = 0.0f;
  if (blockIdx.x == 0 && blockIdx.y == 0) {
    const int t = ty * 32 + tx;
    if (t == 0) out0[0] = 0.0f;
    if (t < ACC_SLOTS * 2) acc[t] = 0.0;
  }
  #pragma unroll
  for (int j = 0; j < 32; j += 8)
    tile[ty + j][tx] = in[(size_t)(by + ty + j) * C + bx + tx];
  __syncthreads();
  #pragma unroll
  for (int j = 0; j < 32; j += 8) {
    const size_t o = (size_t)(bx + ty + j) * C + by + tx;
    supT[o] = tile[tx][ty + j];
    upd[o]  = 0.0f;
  }
}

// ---- kernel A: persistent waves, 4 contiguous rows each, ring prefetch ----
__global__ void ols_label(const float* __restrict__ y,
                          int* __restrict__ labels, int rows_pw) {
  const int wv   = threadIdx.x >> 6;
  const int lane = threadIdx.x & 63;
  const int g    = blockIdx.x * WPB + wv;
  int b = g * rows_pw;

  const float4* cur = reinterpret_cast<const float4*>(y + (size_t)b * CC);
  float4 yb[PF];
  #pragma unroll
  for (int k = 0; k < PF; ++k) yb[k] = cur[k * WAVE + lane];

  for (int r = 0; r < rows_pw; ++r) {
    // next-row pointer (last row: dummy = self, re-reads 4KB of hot L2)
    const float4* nxt = (r + 1 < rows_pw)
        ? reinterpret_cast<const float4*>(y + (size_t)(b + 1) * CC) : cur;
    float lv = -INFINITY; int li = 0x7fffffff;
    #pragma unroll
    for (int k = 0; k < K16; ++k) {
      const float4 v = yb[k & (PF - 1)];     // static idx (unrolled)
      if (k + PF < K16) yb[k & (PF - 1)] = cur[(k + PF) * WAVE + lane];
      else              yb[k & (PF - 1)] = nxt[(k + PF - K16) * WAVE + lane];
      const int base = (k * WAVE + lane) * 4;
      amax2(v.x, base + 0, lv, li);
      amax2(v.y, base + 1, lv, li);
      amax2(v.z, base + 2, lv, li);
      amax2(v.w, base + 3, lv, li);
    }
    // next row's first PF chunks are in flight during this reduce
    wave_argmax(lv, li);
    if (lane == 0) labels[b] = li;
    cur = nxt; ++b;
  }
}

// ---- kernel B: persistent waves, dual ring (y_h + supT row), label a row ahead ----
__global__ void ols_soft(const float* __restrict__ y_h,
                         const int* __restrict__ labels,
                         const float* __restrict__ supT,
                         float* __restrict__ upd, float* __restrict__ cnt,
                         double* __restrict__ acc, int rows_pw, int B) {
  const int wv   = threadIdx.x >> 6;
  const int lane = threadIdx.x & 63;
  const int g    = blockIdx.x * WPB + wv;
  int b = g * rows_pw;

  int lab = labels[b];
  const float4* cur_x = reinterpret_cast<const float4*>(y_h + (size_t)b * CC);
  const float4* cur_w = reinterpret_cast<const float4*>(supT + (size_t)lab * CC);

  float4 xb[PF], wb[PF];
  #pragma unroll
  for (int k = 0; k < PF; ++k) {
    xb[k] = cur_x[k * WAVE + lane];
    wb[k] = cur_w[k * WAVE + lane];
  }

  for (int r = 0; r < rows_pw; ++r) {
    const bool has_next = (r + 1 < rows_pw);
    const int nlab = labels[has_next ? (b + 1) : b];   // a full row early
    const float4* nxt_x = has_next
        ? reinterpret_cast<const float4*>(y_h + (size_t)(b + 1) * CC) : cur_x;
    const float4* nxt_w = has_next
        ? reinterpret_cast<const float4*>(supT + (size_t)nlab * CC) : cur_w;
    const float xl = y_h[(size_t)b * CC + lab];        // for hard loss

    float m = -INFINITY; int mi = 0x7fffffff;
    float s0 = 0.f, W = 0.f, WX = 0.f;
    #pragma unroll
    for (int k = 0; k < K16; ++k) {
      const float4 xv  = xb[k & (PF - 1)];
      const float4 wv4 = wb[k & (PF - 1)];
      if (k + PF < K16) {
        xb[k & (PF - 1)] = cur_x[(k + PF) * WAVE + lane];
        wb[k & (PF - 1)] = cur_w[(k + PF) * WAVE + lane];
      } else {
        xb[k & (PF - 1)] = nxt_x[(k + PF - K16) * WAVE + lane];
        wb[k & (PF - 1)] = nxt_w[(k + PF - K16) * WAVE + lane];
      }
      const int base = (k * WAVE + lane) * 4;
      amax2(xv.x, base + 0, m, mi);
      amax2(xv.y, base + 1, m, mi);
      amax2(xv.z, base + 2, m, mi);
      amax2(xv.w, base + 3, m, mi);
      s0 += __expf(xv.x) + __expf(xv.y) + __expf(xv.z) + __expf(xv.w);
      W  += wv4.x + wv4.y + wv4.z + wv4.w;
      WX += wv4.x * xv.x + wv4.y * xv.y + wv4.z * xv.z + wv4.w * xv.w;
    }
    // next row's chunks in flight during the reduce chain below
    wave_argmax(m, mi);
    const int pred = mi;
    const float Z    = wave_sum(s0);
    const float Wt   = wave_sum(W);
    const float WXt  = wave_sum(WX);
    const float logZ = __logf(Z);
    const float soft = logZ * Wt - WXt;
    const float hard = logZ - xl;

    // rare: correctly-classified row scatters probs into update col `pred`
    if (pred == lab) {
      const float invZ = 1.0f / Z;
      #pragma unroll
      for (int k = 0; k < K16; ++k) {
        const float4 xv = cur_x[k * WAVE + lane];   // L2-hot re-read
        const int base = (k * WAVE + lane) * 4;
        atomicAdd(&upd[(size_t)(base + 0) * CC + pred], __expf(xv.x) * invZ);
        atomicAdd(&upd[(size_t)(base + 1) * CC + pred], __expf(xv.y) * invZ);
        atomicAdd(&upd[(size_t)(base + 2) * CC + pred], __expf(xv.z) * invZ);
        atomicAdd(&upd[(size_t)(base + 3) * CC + pred], __expf(xv.w) * invZ);
      }
      if (lane == 0) atomicAdd(&cnt[pred], 1.0f);
    }

    if (lane == 0) {
      const int slot = (b & (ACC_SLOTS - 1)) * 2;
      atomicAdd(&acc[slot + 0], (double)hard);
      atomicAdd(&acc[slot + 1], (double)soft);
    }
    cur_x = nxt_x; cur_w = nxt_w; lab = nlab; ++b;
  }
}

// ---- fallback fused kernel (only if ws too small for labels buffer) ----
__global__ void ols_fused(const float* __restrict__ y_h, const float* __restrict__ y,
                          const float* __restrict__ supT,
                          float* __restrict__ upd, float* __restrict__ cnt,
                          double* __restrict__ acc) {
  const int wv   = threadIdx.x >> 6;
  const int lane = threadIdx.x & 63;
  const int b    = blockIdx.x * WPB + wv;
  const size_t roff = (size_t)b * CC;
  const float4* y4 = reinterpret_cast<const float4*>(y + roff);
  const float4* x4 = reinterpret_cast<const float4*>(y_h + roff);

  float lv = -INFINITY; int li = 0x7fffffff;
  #pragma unroll 4
  for (int k = 0; k < K16; ++k) {
    const float4 v = y4[k * WAVE + lane];
    const int base = (k * WAVE + lane) * 4;
    amax2(v.x, base + 0, lv, li);
    amax2(v.y, base + 1, lv, li);
    amax2(v.z, base + 2, lv, li);
    amax2(v.w, base + 3, lv, li);
  }
  wave_argmax(lv, li);
  const int y_label = li;
  const float xl = y_h[roff + y_label];
  const float4* w4 = reinterpret_cast<const float4*>(supT + (size_t)y_label * CC);

  float m = -INFINITY; int mi = 0x7fffffff;
  float s0 = 0.f, W = 0.f, WX = 0.f;
  #pragma unroll 4
  for (int k = 0; k < K16; ++k) {
    const float4 xv  = x4[k * WAVE + lane];
    const float4 wv4 = w4[k * WAVE + lane];
    const int base = (k * WAVE + lane) * 4;
    amax2(xv.x, base + 0, m, mi);
    amax2(xv.y, base + 1, m, mi);
    amax2(xv.z, base + 2, m, mi);
    amax2(xv.w, base + 3, m, mi);
    s0 += __expf(xv.x) + __expf(xv.y) + __expf(xv.z) + __expf(xv.w);
    W  += wv4.x + wv4.y + wv4.z + wv4.w;
    WX += wv4.x * xv.x + wv4.y * xv.y + wv4.z * xv.z + wv4.w * xv.w;
  }
  wave_argmax(m, mi);
  const int pred = mi;
  const float Z = wave_sum(s0), Wt = wave_sum(W), WXt = wave_sum(WX);
  const float logZ = __logf(Z);
  const float soft = logZ * Wt - WXt;
  const float hard = logZ - xl;

  if (pred == y_label) {
    const float invZ = 1.0f / Z;
    #pragma unroll 4
    for (int k = 0; k < K16; ++k) {
      const float4 xv = x4[k * WAVE + lane];
      const int base = (k * WAVE + lane) * 4;
      atomicAdd(&upd[(size_t)(base + 0) * CC + pred], __expf(xv.x) * invZ);
      atomicAdd(&upd[(size_t)(base + 1) * CC + pred], __expf(xv.y) * invZ);
      atomicAdd(&upd[(size_t)(base + 2) * CC + pred], __expf(xv.z) * invZ);
      atomicAdd(&upd[(size_t)(base + 3) * CC + pred], __expf(xv.w) * invZ);
    }
    if (lane == 0) atomicAdd(&cnt[pred], 1.0f);
  }
  if (lane == 0) {
    const int slot = (b & (ACC_SLOTS - 1)) * 2;
    atomicAdd(&acc[slot + 0], (double)hard);
    atomicAdd(&acc[slot + 1], (double)soft);
  }
}

__global__ void ols_finalize(const double* __restrict__ acc,
                             float* __restrict__ out, double invB) {
  double h = 0.0, s = 0.0;
  for (int i = 0; i < ACC_SLOTS; ++i) { h += acc[i * 2]; s += acc[i * 2 + 1]; }
  out[0] = (float)(((double)ALPHA_V * h + (1.0 - (double)ALPHA_V) * s) * invB);
}

extern "C" void kernel_launch(void* const* d_in, const int* in_sizes, int n_in,
                              void* d_out, int out_size, void* d_ws, size_t ws_size,
                              hipStream_t stream) {
  const float* y_h = (const float*)d_in[0];
  const float* y   = (const float*)d_in[1];
  const float* sup = (const float*)d_in[2];
  const int C = CC;                       // 4096 (supervise is C*C)
  const int B = in_sizes[0] / C;          // 16384

  float* out        = (float*)d_out;
  float* out_update = out + 1;
  float* out_count  = out + 1 + (size_t)C * C;

  // ws layout: acc @0 (1KB) | labels @4096 (B*4) | supT @4096+B*4 (C*C*4)
  double* acc   = (double*)d_ws;
  int*   labels = (int*)((char*)d_ws + 4096);
  const size_t supT_off_full = 4096 + (size_t)B * 4;      // 16B-aligned
  const size_t need_full = supT_off_full + (size_t)C * C * sizeof(float);
  const bool two_phase = ws_size >= need_full;
  float* supT = (float*)((char*)d_ws + (two_phase ? supT_off_full : 4096));

  {
    dim3 g(C / 32, C / 32), bl(32, 8);
    ols_transpose<<<g, bl, 0, stream>>>(sup, supT, out_update, out,
                                        out_count, acc, C);
  }

  if (two_phase) {
    const int rows_pw = B / (BLOCKS_MAIN * WPB);   // 4
    ols_label<<<BLOCKS_MAIN, TPB, 0, stream>>>(y, labels, rows_pw);
    ols_soft<<<BLOCKS_MAIN, TPB, 0, stream>>>(y_h, labels, supT,
                                              out_update, out_count, acc,
                                              rows_pw, B);
  } else {
    ols_fused<<<B / WPB, TPB, 0, stream>>>(y_h, y, supT,
                                           out_update, out_count, acc);
  }

  ols_finalize<<<1, 1, 0, stream>>>(acc, out, 1.0 / (double)B);
}

// Round 9
// 209.239 us; speedup vs baseline: 2.6639x; 2.6639x over previous
//
#include <hip/hip_runtime.h>
#include <math.h>

// OnlineLabelSmoothing: B=16384 rows, C=4096 classes, f32.
// out = [loss(1), update(C*C), idx_count(C)] f32.
// Round 9: chunk-parallel, tiny-register kernels (demand <55 VGPR so the
// 64-reg/8-wave bucket is safe BY CONSTRUCTION -- r5/r6/r8 all died to
// RA spills on medium-register streaming loops).
//   part_y: wave per (row, 1024-chunk) -> partial {max,idx}
//   part_x: wave per (row, chunk): recompute label from y-partials
//           (broadcast), stream y_h + supT[lab] chunk -> partial
//           {max,idx,sum_exp,sum_w,sum_wx}   (no-max Z + soft=logZ*W-WX,
//           both validated rounds 5-8, absmax 0.0)
//   rowfin: 1 thread/row: reduce 4 partials, losses, match list
//   scatter: update cols for ~4 matched rows + loss finalize

constexpr int CC    = 4096;
constexpr int WAVE  = 64;
constexpr int WPB   = 4;               // waves per block
constexpr int TPB   = 256;
constexpr int NCH   = 4;               // chunks per row
constexpr int CHUNK = CC / NCH;        // 1024 elems
constexpr int JPW   = CHUNK / (WAVE * 4);  // float4 per lane per chunk = 4
constexpr float ALPHA_V = 0.5f;
constexpr int ACC_SLOTS = 64;

__device__ inline void amax2(float v, int i, float& bv, int& bi) {
  // first-occurrence argmax: prefer smaller index on exact tie
  if (v > bv || (v == bv && i < bi)) { bv = v; bi = i; }
}

__device__ inline void wave_argmax(float& lv, int& li) {
  #pragma unroll
  for (int o = 1; o < WAVE; o <<= 1) {
    float ov = __shfl_xor(lv, o, WAVE);
    int   oi = __shfl_xor(li, o, WAVE);
    amax2(ov, oi, lv, li);
  }
}

__device__ inline float wave_sum(float v) {
  #pragma unroll
  for (int o = 1; o < WAVE; o <<= 1) v += __shfl_xor(v, o, WAVE);
  return v;
}

// ---- supervise transpose + zeroing of upd/cnt/acc/mcount ----
__global__ void ols_transpose(const float* __restrict__ in,
                              float* __restrict__ supT,
                              float* __restrict__ upd,
                              float* __restrict__ cnt,
                              double* __restrict__ acc,
                              int* __restrict__ mcount, int C) {
  __shared__ float tile[32][33];
  const int bx = blockIdx.x * 32, by = blockIdx.y * 32;
  const int tx = threadIdx.x, ty = threadIdx.y;  // (32, 8)
  if (blockIdx.y == 0 && ty == 0) cnt[bx + tx] = 0.0f;
  if (blockIdx.x == 0 && blockIdx.y == 0) {
    const int t = ty * 32 + tx;
    if (t == 0) *mcount = 0;
    if (t < ACC_SLOTS * 2) acc[t] = 0.0;
  }
  #pragma unroll
  for (int j = 0; j < 32; j += 8)
    tile[ty + j][tx] = in[(size_t)(by + ty + j) * C + bx + tx];
  __syncthreads();
  #pragma unroll
  for (int j = 0; j < 32; j += 8) {
    const size_t o = (size_t)(bx + ty + j) * C + by + tx;
    supT[o] = tile[tx][ty + j];
    upd[o]  = 0.0f;
  }
}

// ---- K1: per-(row,chunk) argmax partials of y ----
__global__ void ols_part_y(const float* __restrict__ y,
                           float* __restrict__ ypmax,
                           int* __restrict__ ypidx) {
  const int wv = threadIdx.x >> 6, lane = threadIdx.x & 63;
  const int task = blockIdx.x * WPB + wv;        // = b*NCH + ch
  const int b = task >> 2, ch = task & 3;
  const float4* p = reinterpret_cast<const float4*>(y + (size_t)b * CC + ch * CHUNK);

  float4 v[JPW];
  #pragma unroll
  for (int j = 0; j < JPW; ++j) v[j] = p[j * WAVE + lane];

  float m = -INFINITY; int mi = 0x7fffffff;
  #pragma unroll
  for (int j = 0; j < JPW; ++j) {
    const int base = ch * CHUNK + (j * WAVE + lane) * 4;
    amax2(v[j].x, base + 0, m, mi);
    amax2(v[j].y, base + 1, m, mi);
    amax2(v[j].z, base + 2, m, mi);
    amax2(v[j].w, base + 3, m, mi);
  }
  wave_argmax(m, mi);
  if (lane == 0) { ypmax[task] = m; ypidx[task] = mi; }
}

// ---- K3: per-(row,chunk) partials of y_h + supT[label] ----
__global__ void ols_part_x(const float* __restrict__ y_h,
                           const float* __restrict__ supT,
                           const float* __restrict__ ypmax,
                           const int* __restrict__ ypidx,
                           float* __restrict__ xpmax, int* __restrict__ xpidx,
                           float* __restrict__ xpse, float* __restrict__ xpW,
                           float* __restrict__ xpWX) {
  const int wv = threadIdx.x >> 6, lane = threadIdx.x & 63;
  const int task = blockIdx.x * WPB + wv;
  const int b = task >> 2, ch = task & 3;

  // wave-uniform label recompute from y-partials (broadcast loads)
  const float4 ym = reinterpret_cast<const float4*>(ypmax)[b];
  const int4   yi = reinterpret_cast<const int4*>(ypidx)[b];
  float lm = ym.x; int lab = yi.x;
  amax2(ym.y, yi.y, lm, lab);
  amax2(ym.z, yi.z, lm, lab);
  amax2(ym.w, yi.w, lm, lab);

  const float4* px = reinterpret_cast<const float4*>(y_h + (size_t)b * CC + ch * CHUNK);
  const float4* pw = reinterpret_cast<const float4*>(supT + (size_t)lab * CC + ch * CHUNK);

  float4 xv[JPW], wv4[JPW];
  #pragma unroll
  for (int j = 0; j < JPW; ++j) xv[j] = px[j * WAVE + lane];
  #pragma unroll
  for (int j = 0; j < JPW; ++j) wv4[j] = pw[j * WAVE + lane];

  float m = -INFINITY; int mi = 0x7fffffff;
  float se = 0.f, W = 0.f, WX = 0.f;
  #pragma unroll
  for (int j = 0; j < JPW; ++j) {
    const int base = ch * CHUNK + (j * WAVE + lane) * 4;
    amax2(xv[j].x, base + 0, m, mi);
    amax2(xv[j].y, base + 1, m, mi);
    amax2(xv[j].z, base + 2, m, mi);
    amax2(xv[j].w, base + 3, m, mi);
    se += __expf(xv[j].x) + __expf(xv[j].y) + __expf(xv[j].z) + __expf(xv[j].w);
    W  += wv4[j].x + wv4[j].y + wv4[j].z + wv4[j].w;
    WX += wv4[j].x * xv[j].x + wv4[j].y * xv[j].y
        + wv4[j].z * xv[j].z + wv4[j].w * xv[j].w;
  }
  wave_argmax(m, mi);
  se = wave_sum(se);
  W  = wave_sum(W);
  WX = wave_sum(WX);
  if (lane == 0) {
    xpmax[task] = m; xpidx[task] = mi;
    xpse[task] = se; xpW[task] = W; xpWX[task] = WX;
  }
}

// ---- K4: one thread per row: reduce partials, losses, match list ----
__global__ void ols_rowfin(const float* __restrict__ y_h,
                           const float* __restrict__ ypmax, const int* __restrict__ ypidx,
                           const float* __restrict__ xpmax, const int* __restrict__ xpidx,
                           const float* __restrict__ xpse, const float* __restrict__ xpW,
                           const float* __restrict__ xpWX,
                           float* __restrict__ Zbuf,
                           int2* __restrict__ matches, int* __restrict__ mcount,
                           float* __restrict__ cnt, double* __restrict__ acc) {
  const int b = blockIdx.x * TPB + threadIdx.x;

  const float4 ym = reinterpret_cast<const float4*>(ypmax)[b];
  const int4   yi = reinterpret_cast<const int4*>(ypidx)[b];
  float lm = ym.x; int lab = yi.x;
  amax2(ym.y, yi.y, lm, lab);
  amax2(ym.z, yi.z, lm, lab);
  amax2(ym.w, yi.w, lm, lab);

  const float4 xm = reinterpret_cast<const float4*>(xpmax)[b];
  const int4   xi = reinterpret_cast<const int4*>(xpidx)[b];
  float pm = xm.x; int pred = xi.x;
  amax2(xm.y, xi.y, pm, pred);
  amax2(xm.z, xi.z, pm, pred);
  amax2(xm.w, xi.w, pm, pred);

  const float4 se4 = reinterpret_cast<const float4*>(xpse)[b];
  const float4 W4  = reinterpret_cast<const float4*>(xpW)[b];
  const float4 WX4 = reinterpret_cast<const float4*>(xpWX)[b];
  const float Z  = se4.x + se4.y + se4.z + se4.w;
  const float W  = W4.x + W4.y + W4.z + W4.w;
  const float WX = WX4.x + WX4.y + WX4.z + WX4.w;

  const float logZ = __logf(Z);
  const float xl   = y_h[(size_t)b * CC + lab];
  float soft = logZ * W - WX;
  float hard = logZ - xl;
  Zbuf[b] = Z;

  if (pred == lab) {
    const int pos = atomicAdd(mcount, 1);
    matches[pos] = make_int2(b, pred);
    atomicAdd(&cnt[pred], 1.0f);
  }

  hard = wave_sum(hard);
  soft = wave_sum(soft);
  if ((threadIdx.x & 63) == 0) {
    const int slot = ((b >> 6) & (ACC_SLOTS - 1)) * 2;
    atomicAdd(&acc[slot + 0], (double)hard);
    atomicAdd(&acc[slot + 1], (double)soft);
  }
}

// ---- K5: scatter update for matched rows + loss finalize ----
__global__ void ols_scatter(const float* __restrict__ y_h,
                            const int2* __restrict__ matches,
                            const int* __restrict__ mcount,
                            const float* __restrict__ Zbuf,
                            float* __restrict__ upd,
                            const double* __restrict__ acc,
                            float* __restrict__ out0, double invB) {
  if (blockIdx.x == 0 && threadIdx.x == 0) {
    double h = 0.0, s = 0.0;
    for (int i = 0; i < ACC_SLOTS; ++i) { h += acc[i * 2]; s += acc[i * 2 + 1]; }
    out0[0] = (float)(((double)ALPHA_V * h + (1.0 - (double)ALPHA_V) * s) * invB);
  }
  const int n = *mcount;
  for (int i = blockIdx.x; i < n; i += gridDim.x) {
    const int2 mr = matches[i];
    const int b = mr.x, pred = mr.y;
    const float invZ = 1.0f / Zbuf[b];
    const float4* px = reinterpret_cast<const float4*>(y_h + (size_t)b * CC);
    #pragma unroll
    for (int j = 0; j < 4; ++j) {
      const int i4 = j * TPB + threadIdx.x;
      const float4 xv = px[i4];
      const int base = i4 * 4;
      atomicAdd(&upd[(size_t)(base + 0) * CC + pred], __expf(xv.x) * invZ);
      atomicAdd(&upd[(size_t)(base + 1) * CC + pred], __expf(xv.y) * invZ);
      atomicAdd(&upd[(size_t)(base + 2) * CC + pred], __expf(xv.z) * invZ);
      atomicAdd(&upd[(size_t)(base + 3) * CC + pred], __expf(xv.w) * invZ);
    }
  }
}

// ---- fallback (tiny ws): fused per-row kernel, direct sup column reads ----
__global__ void ols_fallback(const float* __restrict__ y_h, const float* __restrict__ y,
                             const float* __restrict__ sup,
                             float* __restrict__ upd, float* __restrict__ cnt,
                             double* __restrict__ acc) {
  const int wv = threadIdx.x >> 6, lane = threadIdx.x & 63;
  const int b = blockIdx.x * WPB + wv;
  const size_t roff = (size_t)b * CC;
  const float4* y4 = reinterpret_cast<const float4*>(y + roff);
  const float4* x4 = reinterpret_cast<const float4*>(y_h + roff);
  const int K16 = CC / (WAVE * 4);

  float lv = -INFINITY; int li = 0x7fffffff;
  for (int k = 0; k < K16; ++k) {
    const float4 v = y4[k * WAVE + lane];
    const int base = (k * WAVE + lane) * 4;
    amax2(v.x, base + 0, lv, li); amax2(v.y, base + 1, lv, li);
    amax2(v.z, base + 2, lv, li); amax2(v.w, base + 3, lv, li);
  }
  wave_argmax(lv, li);
  const int lab = li;
  const float xl = y_h[roff + lab];

  float m = -INFINITY; int mi = 0x7fffffff;
  float se = 0.f, W = 0.f, WX = 0.f;
  for (int k = 0; k < K16; ++k) {
    const float4 xv = x4[k * WAVE + lane];
    const int base = (k * WAVE + lane) * 4;
    const float w0 = sup[(size_t)(base + 0) * CC + lab];
    const float w1 = sup[(size_t)(base + 1) * CC + lab];
    const float w2 = sup[(size_t)(base + 2) * CC + lab];
    const float w3 = sup[(size_t)(base + 3) * CC + lab];
    amax2(xv.x, base + 0, m, mi); amax2(xv.y, base + 1, m, mi);
    amax2(xv.z, base + 2, m, mi); amax2(xv.w, base + 3, m, mi);
    se += __expf(xv.x) + __expf(xv.y) + __expf(xv.z) + __expf(xv.w);
    W  += w0 + w1 + w2 + w3;
    WX += w0 * xv.x + w1 * xv.y + w2 * xv.z + w3 * xv.w;
  }
  wave_argmax(m, mi);
  const int pred = mi;
  const float Z = wave_sum(se), Wt = wave_sum(W), WXt = wave_sum(WX);
  const float logZ = __logf(Z);
  if (pred == lab) {
    const float invZ = 1.0f / Z;
    for (int k = 0; k < K16; ++k) {
      const float4 xv = x4[k * WAVE + lane];
      const int base = (k * WAVE + lane) * 4;
      atomicAdd(&upd[(size_t)(base + 0) * CC + pred], __expf(xv.x) * invZ);
      atomicAdd(&upd[(size_t)(base + 1) * CC + pred], __expf(xv.y) * invZ);
      atomicAdd(&upd[(size_t)(base + 2) * CC + pred], __expf(xv.z) * invZ);
      atomicAdd(&upd[(size_t)(base + 3) * CC + pred], __expf(xv.w) * invZ);
    }
    if (lane == 0) atomicAdd(&cnt[pred], 1.0f);
  }
  if (lane == 0) {
    const int slot = (b & (ACC_SLOTS - 1)) * 2;
    atomicAdd(&acc[slot + 0], (double)(logZ - xl));
    atomicAdd(&acc[slot + 1], (double)(logZ * Wt - WXt));
  }
}

__global__ void ols_finalize(const double* __restrict__ acc,
                             float* __restrict__ out, double invB) {
  double h = 0.0, s = 0.0;
  for (int i = 0; i < ACC_SLOTS; ++i) { h += acc[i * 2]; s += acc[i * 2 + 1]; }
  out[0] = (float)(((double)ALPHA_V * h + (1.0 - (double)ALPHA_V) * s) * invB);
}

extern "C" void kernel_launch(void* const* d_in, const int* in_sizes, int n_in,
                              void* d_out, int out_size, void* d_ws, size_t ws_size,
                              hipStream_t stream) {
  const float* y_h = (const float*)d_in[0];
  const float* y   = (const float*)d_in[1];
  const float* sup = (const float*)d_in[2];
  const int C = CC;                       // 4096 (supervise is C*C)
  const int B = in_sizes[0] / C;          // 16384

  float* out        = (float*)d_out;
  float* out_update = out + 1;
  float* out_count  = out + 1 + (size_t)C * C;

  // ws layout (all 16B-aligned)
  char* ws = (char*)d_ws;
  double* acc    = (double*)ws;                       // 1 KB
  int*    mcount = (int*)(ws + 1024);
  float*  Zbuf   = (float*)(ws + 4096);               // B*4   = 64 KB
  int2*   matches= (int2*)(ws + 69632);               // B*8   = 128 KB
  float*  ypmax  = (float*)(ws + 200704);             // B*4*4 = 256 KB each
  int*    ypidx  = (int*)  (ws + 462848);
  float*  xpmax  = (float*)(ws + 724992);
  int*    xpidx  = (int*)  (ws + 987136);
  float*  xpse   = (float*)(ws + 1249280);
  float*  xpW    = (float*)(ws + 1511424);
  float*  xpWX   = (float*)(ws + 1773568);
  float*  supT   = (float*)(ws + 2035712);            // C*C*4 = 64 MB
  const size_t need = 2035712 + (size_t)C * C * sizeof(float);

  if (ws_size >= need) {
    dim3 g(C / 32, C / 32), bl(32, 8);
    ols_transpose<<<g, bl, 0, stream>>>(sup, supT, out_update, out_count,
                                        acc, mcount, C);
    ols_part_y<<<B * NCH / WPB, TPB, 0, stream>>>(y, ypmax, ypidx);
    ols_part_x<<<B * NCH / WPB, TPB, 0, stream>>>(y_h, supT, ypmax, ypidx,
                                                  xpmax, xpidx, xpse, xpW, xpWX);
    ols_rowfin<<<B / TPB, TPB, 0, stream>>>(y_h, ypmax, ypidx,
                                            xpmax, xpidx, xpse, xpW, xpWX,
                                            Zbuf, matches, mcount,
                                            out_count, acc);
    ols_scatter<<<64, TPB, 0, stream>>>(y_h, matches, mcount, Zbuf,
                                        out_update, acc, out, 1.0 / (double)B);
  } else {
    hipMemsetAsync(d_out, 0, (size_t)out_size * sizeof(float), stream);
    hipMemsetAsync(d_ws, 0, 4096, stream);
    ols_fallback<<<B / WPB, TPB, 0, stream>>>(y_h, y, sup,
                                              out_update, out_count, acc);
    ols_finalize<<<1, 1, 0, stream>>>(acc, out, 1.0 / (double)B);
  }
}

// Round 10
// 196.833 us; speedup vs baseline: 2.8319x; 1.0630x over previous
//
#include <hip/hip_runtime.h>
#include <math.h>

// OnlineLabelSmoothing: B=16384 rows, C=4096 classes, f32.
// out = [loss(1), update(C*C), idx_count(C)] f32.
// Round 10: r9 structure (chunk-parallel tiny-register kernels, no spills)
// with launch-graph compression:
//   mega:   even blocks = sup transpose tile (+upd zeroing),
//           odd blocks  = part_y (y argmax partials)  -- independent work
//           overlapped on HBM read+write ports instead of serialized.
//   part_x: unchanged from r9 (proven no-spill, VGPR<64).
//   rowfin: partial-reduce + losses + BLOCK-LOCAL match scatter (fused,
//           removes scatter kernel + Zbuf/matches/mcount buffers).
//   finalize: 1 thread.

constexpr int CC    = 4096;
constexpr int WAVE  = 64;
constexpr int WPB   = 4;               // waves per block
constexpr int TPB   = 256;
constexpr int NCH   = 4;               // chunks per row
constexpr int CHUNK = CC / NCH;        // 1024 elems
constexpr int JPW   = CHUNK / (WAVE * 4);  // float4 per lane per chunk = 4
constexpr float ALPHA_V = 0.5f;
constexpr int ACC_SLOTS = 64;
constexpr int MCAP  = 32;              // per-block match capacity (exp ~0.06)

__device__ inline void amax2(float v, int i, float& bv, int& bi) {
  // first-occurrence argmax: prefer smaller index on exact tie
  if (v > bv || (v == bv && i < bi)) { bv = v; bi = i; }
}

__device__ inline void wave_argmax(float& lv, int& li) {
  #pragma unroll
  for (int o = 1; o < WAVE; o <<= 1) {
    float ov = __shfl_xor(lv, o, WAVE);
    int   oi = __shfl_xor(li, o, WAVE);
    amax2(ov, oi, lv, li);
  }
}

__device__ inline float wave_sum(float v) {
  #pragma unroll
  for (int o = 1; o < WAVE; o <<= 1) v += __shfl_xor(v, o, WAVE);
  return v;
}

// ---- mega: interleaved transpose(+zeroing) | part_y ----
__global__ void ols_mega(const float* __restrict__ sup,
                         float* __restrict__ supT,
                         float* __restrict__ upd,
                         float* __restrict__ cnt,
                         double* __restrict__ acc,
                         const float* __restrict__ y,
                         float* __restrict__ ypmax,
                         int* __restrict__ ypidx, int C) {
  __shared__ float tile[32][33];
  const int blk = blockIdx.x;
  if ((blk & 1) == 0) {
    // ---- transpose tile (32x32), threads decoded as (32,8) ----
    const int tid = threadIdx.x;
    const int t2 = blk >> 1;
    const int bx = (t2 & 127) * 32, by = (t2 >> 7) * 32;
    const int tx = tid & 31, ty = tid >> 5;
    if (by == 0 && ty == 0) cnt[bx + tx] = 0.0f;
    if (t2 == 0 && tid < ACC_SLOTS * 2) acc[tid] = 0.0;
    #pragma unroll
    for (int j = 0; j < 32; j += 8)
      tile[ty + j][tx] = sup[(size_t)(by + ty + j) * C + bx + tx];
    __syncthreads();
    #pragma unroll
    for (int j = 0; j < 32; j += 8) {
      const size_t o = (size_t)(bx + ty + j) * C + by + tx;
      supT[o] = tile[tx][ty + j];
      upd[o]  = 0.0f;
    }
  } else {
    // ---- part_y: 4 waves, one (row,chunk) task each ----
    const int wv = threadIdx.x >> 6, lane = threadIdx.x & 63;
    const int task = (blk >> 1) * WPB + wv;        // = b*NCH + ch
    const int b = task >> 2, ch = task & 3;
    const float4* p = reinterpret_cast<const float4*>(y + (size_t)b * CC + ch * CHUNK);

    float4 v[JPW];
    #pragma unroll
    for (int j = 0; j < JPW; ++j) v[j] = p[j * WAVE + lane];

    float m = -INFINITY; int mi = 0x7fffffff;
    #pragma unroll
    for (int j = 0; j < JPW; ++j) {
      const int base = ch * CHUNK + (j * WAVE + lane) * 4;
      amax2(v[j].x, base + 0, m, mi);
      amax2(v[j].y, base + 1, m, mi);
      amax2(v[j].z, base + 2, m, mi);
      amax2(v[j].w, base + 3, m, mi);
    }
    wave_argmax(m, mi);
    if (lane == 0) { ypmax[task] = m; ypidx[task] = mi; }
  }
}

// ---- part_x: per-(row,chunk) partials of y_h + supT[label] (r9-identical) ----
__global__ void ols_part_x(const float* __restrict__ y_h,
                           const float* __restrict__ supT,
                           const float* __restrict__ ypmax,
                           const int* __restrict__ ypidx,
                           float* __restrict__ xpmax, int* __restrict__ xpidx,
                           float* __restrict__ xpse, float* __restrict__ xpW,
                           float* __restrict__ xpWX) {
  const int wv = threadIdx.x >> 6, lane = threadIdx.x & 63;
  const int task = blockIdx.x * WPB + wv;
  const int b = task >> 2, ch = task & 3;

  // wave-uniform label recompute from y-partials (broadcast loads)
  const float4 ym = reinterpret_cast<const float4*>(ypmax)[b];
  const int4   yi = reinterpret_cast<const int4*>(ypidx)[b];
  float lm = ym.x; int lab = yi.x;
  amax2(ym.y, yi.y, lm, lab);
  amax2(ym.z, yi.z, lm, lab);
  amax2(ym.w, yi.w, lm, lab);

  const float4* px = reinterpret_cast<const float4*>(y_h + (size_t)b * CC + ch * CHUNK);
  const float4* pw = reinterpret_cast<const float4*>(supT + (size_t)lab * CC + ch * CHUNK);

  float4 xv[JPW], wv4[JPW];
  #pragma unroll
  for (int j = 0; j < JPW; ++j) xv[j] = px[j * WAVE + lane];
  #pragma unroll
  for (int j = 0; j < JPW; ++j) wv4[j] = pw[j * WAVE + lane];

  float m = -INFINITY; int mi = 0x7fffffff;
  float se = 0.f, W = 0.f, WX = 0.f;
  #pragma unroll
  for (int j = 0; j < JPW; ++j) {
    const int base = ch * CHUNK + (j * WAVE + lane) * 4;
    amax2(xv[j].x, base + 0, m, mi);
    amax2(xv[j].y, base + 1, m, mi);
    amax2(xv[j].z, base + 2, m, mi);
    amax2(xv[j].w, base + 3, m, mi);
    se += __expf(xv[j].x) + __expf(xv[j].y) + __expf(xv[j].z) + __expf(xv[j].w);
    W  += wv4[j].x + wv4[j].y + wv4[j].z + wv4[j].w;
    WX += wv4[j].x * xv[j].x + wv4[j].y * xv[j].y
        + wv4[j].z * xv[j].z + wv4[j].w * xv[j].w;
  }
  wave_argmax(m, mi);
  se = wave_sum(se);
  W  = wave_sum(W);
  WX = wave_sum(WX);
  if (lane == 0) {
    xpmax[task] = m; xpidx[task] = mi;
    xpse[task] = se; xpW[task] = W; xpWX[task] = WX;
  }
}

// ---- rowfin: reduce partials, losses, fused block-local match scatter ----
__global__ void ols_rowfin(const float* __restrict__ y_h,
                           const float* __restrict__ ypmax, const int* __restrict__ ypidx,
                           const float* __restrict__ xpmax, const int* __restrict__ xpidx,
                           const float* __restrict__ xpse, const float* __restrict__ xpW,
                           const float* __restrict__ xpWX,
                           float* __restrict__ upd,
                           float* __restrict__ cnt, double* __restrict__ acc) {
  __shared__ int   s_n;
  __shared__ int   s_row[MCAP];
  __shared__ int   s_pred[MCAP];
  __shared__ float s_invZ[MCAP];
  const int tid = threadIdx.x;
  const int b = blockIdx.x * TPB + tid;
  if (tid == 0) s_n = 0;

  const float4 ym = reinterpret_cast<const float4*>(ypmax)[b];
  const int4   yi = reinterpret_cast<const int4*>(ypidx)[b];
  float lm = ym.x; int lab = yi.x;
  amax2(ym.y, yi.y, lm, lab);
  amax2(ym.z, yi.z, lm, lab);
  amax2(ym.w, yi.w, lm, lab);

  const float4 xm = reinterpret_cast<const float4*>(xpmax)[b];
  const int4   xi = reinterpret_cast<const int4*>(xpidx)[b];
  float pm = xm.x; int pred = xi.x;
  amax2(xm.y, xi.y, pm, pred);
  amax2(xm.z, xi.z, pm, pred);
  amax2(xm.w, xi.w, pm, pred);

  const float4 se4 = reinterpret_cast<const float4*>(xpse)[b];
  const float4 W4  = reinterpret_cast<const float4*>(xpW)[b];
  const float4 WX4 = reinterpret_cast<const float4*>(xpWX)[b];
  const float Z  = se4.x + se4.y + se4.z + se4.w;
  const float W  = W4.x + W4.y + W4.z + W4.w;
  const float WX = WX4.x + WX4.y + WX4.z + WX4.w;

  const float logZ = __logf(Z);
  const float xl   = y_h[(size_t)b * CC + lab];
  float soft = logZ * W - WX;
  float hard = logZ - xl;

  __syncthreads();   // s_n=0 visible
  bool overflow = false;
  if (pred == lab) {
    const int pos = atomicAdd(&s_n, 1);
    if (pos < MCAP) { s_row[pos] = b; s_pred[pos] = pred; s_invZ[pos] = 1.0f / Z; }
    else overflow = true;
    atomicAdd(&cnt[pred], 1.0f);
  }
  // (astronomically unlikely) overflow fallback: this thread scatters alone
  if (overflow) {
    const float invZ = 1.0f / Z;
    const float* xr = y_h + (size_t)b * CC;
    for (int c = 0; c < CC; ++c)
      atomicAdd(&upd[(size_t)c * CC + pred], __expf(xr[c]) * invZ);
  }

  hard = wave_sum(hard);
  soft = wave_sum(soft);
  if ((tid & 63) == 0) {
    const int slot = ((b >> 6) & (ACC_SLOTS - 1)) * 2;
    atomicAdd(&acc[slot + 0], (double)hard);
    atomicAdd(&acc[slot + 1], (double)soft);
  }

  __syncthreads();
  const int n = min(s_n, MCAP);
  for (int i = 0; i < n; ++i) {
    const int rb = s_row[i], p = s_pred[i];
    const float iz = s_invZ[i];
    const float4* px = reinterpret_cast<const float4*>(y_h + (size_t)rb * CC);
    #pragma unroll
    for (int j = 0; j < 4; ++j) {
      const int i4 = j * TPB + tid;
      const float4 xv = px[i4];
      const int base = i4 * 4;
      atomicAdd(&upd[(size_t)(base + 0) * CC + p], __expf(xv.x) * iz);
      atomicAdd(&upd[(size_t)(base + 1) * CC + p], __expf(xv.y) * iz);
      atomicAdd(&upd[(size_t)(base + 2) * CC + p], __expf(xv.z) * iz);
      atomicAdd(&upd[(size_t)(base + 3) * CC + p], __expf(xv.w) * iz);
    }
  }
}

__global__ void ols_finalize(const double* __restrict__ acc,
                             float* __restrict__ out, double invB) {
  double h = 0.0, s = 0.0;
  for (int i = 0; i < ACC_SLOTS; ++i) { h += acc[i * 2]; s += acc[i * 2 + 1]; }
  out[0] = (float)(((double)ALPHA_V * h + (1.0 - (double)ALPHA_V) * s) * invB);
}

// ---- fallback (tiny ws): fused per-row kernel, direct sup column reads ----
__global__ void ols_fallback(const float* __restrict__ y_h, const float* __restrict__ y,
                             const float* __restrict__ sup,
                             float* __restrict__ upd, float* __restrict__ cnt,
                             double* __restrict__ acc) {
  const int wv = threadIdx.x >> 6, lane = threadIdx.x & 63;
  const int b = blockIdx.x * WPB + wv;
  const size_t roff = (size_t)b * CC;
  const float4* y4 = reinterpret_cast<const float4*>(y + roff);
  const float4* x4 = reinterpret_cast<const float4*>(y_h + roff);
  const int K16 = CC / (WAVE * 4);

  float lv = -INFINITY; int li = 0x7fffffff;
  for (int k = 0; k < K16; ++k) {
    const float4 v = y4[k * WAVE + lane];
    const int base = (k * WAVE + lane) * 4;
    amax2(v.x, base + 0, lv, li); amax2(v.y, base + 1, lv, li);
    amax2(v.z, base + 2, lv, li); amax2(v.w, base + 3, lv, li);
  }
  wave_argmax(lv, li);
  const int lab = li;
  const float xl = y_h[roff + lab];

  float m = -INFINITY; int mi = 0x7fffffff;
  float se = 0.f, W = 0.f, WX = 0.f;
  for (int k = 0; k < K16; ++k) {
    const float4 xv = x4[k * WAVE + lane];
    const int base = (k * WAVE + lane) * 4;
    const float w0 = sup[(size_t)(base + 0) * CC + lab];
    const float w1 = sup[(size_t)(base + 1) * CC + lab];
    const float w2 = sup[(size_t)(base + 2) * CC + lab];
    const float w3 = sup[(size_t)(base + 3) * CC + lab];
    amax2(xv.x, base + 0, m, mi); amax2(xv.y, base + 1, m, mi);
    amax2(xv.z, base + 2, m, mi); amax2(xv.w, base + 3, m, mi);
    se += __expf(xv.x) + __expf(xv.y) + __expf(xv.z) + __expf(xv.w);
    W  += w0 + w1 + w2 + w3;
    WX += w0 * xv.x + w1 * xv.y + w2 * xv.z + w3 * xv.w;
  }
  wave_argmax(m, mi);
  const int pred = mi;
  const float Z = wave_sum(se), Wt = wave_sum(W), WXt = wave_sum(WX);
  const float logZ = __logf(Z);
  if (pred == lab) {
    const float invZ = 1.0f / Z;
    for (int k = 0; k < K16; ++k) {
      const float4 xv = x4[k * WAVE + lane];
      const int base = (k * WAVE + lane) * 4;
      atomicAdd(&upd[(size_t)(base + 0) * CC + pred], __expf(xv.x) * invZ);
      atomicAdd(&upd[(size_t)(base + 1) * CC + pred], __expf(xv.y) * invZ);
      atomicAdd(&upd[(size_t)(base + 2) * CC + pred], __expf(xv.z) * invZ);
      atomicAdd(&upd[(size_t)(base + 3) * CC + pred], __expf(xv.w) * invZ);
    }
    if (lane == 0) atomicAdd(&cnt[pred], 1.0f);
  }
  if (lane == 0) {
    const int slot = (b & (ACC_SLOTS - 1)) * 2;
    atomicAdd(&acc[slot + 0], (double)(logZ - xl));
    atomicAdd(&acc[slot + 1], (double)(logZ * Wt - WXt));
  }
}

extern "C" void kernel_launch(void* const* d_in, const int* in_sizes, int n_in,
                              void* d_out, int out_size, void* d_ws, size_t ws_size,
                              hipStream_t stream) {
  const float* y_h = (const float*)d_in[0];
  const float* y   = (const float*)d_in[1];
  const float* sup = (const float*)d_in[2];
  const int C = CC;                       // 4096 (supervise is C*C)
  const int B = in_sizes[0] / C;          // 16384

  float* out        = (float*)d_out;
  float* out_update = out + 1;
  float* out_count  = out + 1 + (size_t)C * C;

  // ws layout (all 16B-aligned)
  char* ws = (char*)d_ws;
  double* acc   = (double*)ws;                        // 1 KB
  float*  ypmax = (float*)(ws + 4096);                // B*NCH*4 = 256 KB each
  int*    ypidx = (int*)  (ws + 266240);
  float*  xpmax = (float*)(ws + 528384);
  int*    xpidx = (int*)  (ws + 790528);
  float*  xpse  = (float*)(ws + 1052672);
  float*  xpW   = (float*)(ws + 1314816);
  float*  xpWX  = (float*)(ws + 1576960);
  float*  supT  = (float*)(ws + 1839104);             // C*C*4 = 64 MB
  const size_t need = 1839104 + (size_t)C * C * sizeof(float);

  if (ws_size >= need) {
    // transpose tiles: (C/32)^2 = 16384; part_y groups: B*NCH/WPB = 16384
    ols_mega<<<32768, TPB, 0, stream>>>(sup, supT, out_update, out_count,
                                        acc, y, ypmax, ypidx, C);
    ols_part_x<<<B * NCH / WPB, TPB, 0, stream>>>(y_h, supT, ypmax, ypidx,
                                                  xpmax, xpidx, xpse, xpW, xpWX);
    ols_rowfin<<<B / TPB, TPB, 0, stream>>>(y_h, ypmax, ypidx,
                                            xpmax, xpidx, xpse, xpW, xpWX,
                                            out_update, out_count, acc);
    ols_finalize<<<1, 1, 0, stream>>>(acc, out, 1.0 / (double)B);
  } else {
    hipMemsetAsync(d_out, 0, (size_t)out_size * sizeof(float), stream);
    hipMemsetAsync(d_ws, 0, 4096, stream);
    ols_fallback<<<B / WPB, TPB, 0, stream>>>(y_h, y, sup,
                                              out_update, out_count, acc);
    ols_finalize<<<1, 1, 0, stream>>>(acc, out, 1.0 / (double)B);
  }
}

// Round 11
// 191.012 us; speedup vs baseline: 2.9182x; 1.0305x over previous
//
#include <hip/hip_runtime.h>
#include <math.h>

// OnlineLabelSmoothing: B=16384 rows, C=4096 classes, f32.
// out = [loss(1), update(C*C), idx_count(C)] f32.
// Round 11: block=row alignment so all reduction tails happen in-LDS:
//   mega:    even blocks = sup transpose tile (+upd/cnt/acc zeroing),
//            odd blocks  = per-ROW y argmax (4 waves x 1024-chunk,
//            LDS reduce) -> labels[b]  (no partial buffers)
//   ols_row: block per row: 4 waves stream y_h + supT[lab] chunks
//            (r9-proven inner loop, VGPR<=64), LDS reduce, losses,
//            INLINE match scatter (row is L2-hot). rowfin eliminated.
//   finalize: 1 thread.
// 3 launches; only labels (64 KB) round-trips between kernels.

constexpr int CC    = 4096;
constexpr int WAVE  = 64;
constexpr int WPB   = 4;               // waves per block
constexpr int TPB   = 256;
constexpr int CHUNK = CC / WPB;        // 1024 elems per wave
constexpr int JPW   = CHUNK / (WAVE * 4);  // float4 per lane per chunk = 4
constexpr float ALPHA_V = 0.5f;
constexpr int ACC_SLOTS = 64;

__device__ inline void amax2(float v, int i, float& bv, int& bi) {
  // first-occurrence argmax: prefer smaller index on exact tie
  if (v > bv || (v == bv && i < bi)) { bv = v; bi = i; }
}

__device__ inline void wave_argmax(float& lv, int& li) {
  #pragma unroll
  for (int o = 1; o < WAVE; o <<= 1) {
    float ov = __shfl_xor(lv, o, WAVE);
    int   oi = __shfl_xor(li, o, WAVE);
    amax2(ov, oi, lv, li);
  }
}

__device__ inline float wave_sum(float v) {
  #pragma unroll
  for (int o = 1; o < WAVE; o <<= 1) v += __shfl_xor(v, o, WAVE);
  return v;
}

// ---- mega: even blocks transpose(+zeroing), odd blocks per-row y argmax ----
__global__ void ols_mega(const float* __restrict__ sup,
                         float* __restrict__ supT,
                         float* __restrict__ upd,
                         float* __restrict__ cnt,
                         double* __restrict__ acc,
                         const float* __restrict__ y,
                         int* __restrict__ labels, int C) {
  __shared__ float tile[32][33];
  __shared__ float s_m[WPB];
  __shared__ int   s_i[WPB];
  const int blk = blockIdx.x;
  const int tid = threadIdx.x;
  if ((blk & 1) == 0) {
    // ---- transpose tile (32x32), threads decoded as (32,8) ----
    const int t2 = blk >> 1;
    const int bx = (t2 & 127) * 32, by = (t2 >> 7) * 32;
    const int tx = tid & 31, ty = tid >> 5;
    if (by == 0 && ty == 0) cnt[bx + tx] = 0.0f;
    if (t2 == 0 && tid < ACC_SLOTS * 2) acc[tid] = 0.0;
    #pragma unroll
    for (int j = 0; j < 32; j += 8)
      tile[ty + j][tx] = sup[(size_t)(by + ty + j) * C + bx + tx];
    __syncthreads();
    #pragma unroll
    for (int j = 0; j < 32; j += 8) {
      const size_t o = (size_t)(bx + ty + j) * C + by + tx;
      supT[o] = tile[tx][ty + j];
      upd[o]  = 0.0f;
    }
  } else {
    // ---- per-row y argmax: wave wv handles chunk wv ----
    const int wv = tid >> 6, lane = tid & 63;
    const int b = blk >> 1;
    const float4* p = reinterpret_cast<const float4*>(y + (size_t)b * CC)
                      + wv * (CHUNK / 4);
    float4 v[JPW];
    #pragma unroll
    for (int j = 0; j < JPW; ++j) v[j] = p[j * WAVE + lane];

    float m = -INFINITY; int mi = 0x7fffffff;
    #pragma unroll
    for (int j = 0; j < JPW; ++j) {
      const int base = wv * CHUNK + (j * WAVE + lane) * 4;
      amax2(v[j].x, base + 0, m, mi);
      amax2(v[j].y, base + 1, m, mi);
      amax2(v[j].z, base + 2, m, mi);
      amax2(v[j].w, base + 3, m, mi);
    }
    wave_argmax(m, mi);
    if (lane == 0) { s_m[wv] = m; s_i[wv] = mi; }
    __syncthreads();
    if (tid == 0) {
      float bm = s_m[0]; int bi = s_i[0];
      amax2(s_m[1], s_i[1], bm, bi);
      amax2(s_m[2], s_i[2], bm, bi);
      amax2(s_m[3], s_i[3], bm, bi);
      labels[b] = bi;
    }
  }
}

// ---- ols_row: block per row; stream y_h + supT[lab]; losses + scatter ----
__global__ void ols_row(const float* __restrict__ y_h,
                        const int* __restrict__ labels,
                        const float* __restrict__ supT,
                        float* __restrict__ upd, float* __restrict__ cnt,
                        double* __restrict__ acc) {
  __shared__ float s_m[WPB], s_se[WPB], s_W[WPB], s_WX[WPB];
  __shared__ int   s_mi[WPB];
  const int tid = threadIdx.x;
  const int wv = tid >> 6, lane = tid & 63;
  const int b = blockIdx.x;
  const int lab = labels[b];
  const size_t roff = (size_t)b * CC;

  const float4* px = reinterpret_cast<const float4*>(y_h + roff) + wv * (CHUNK / 4);
  const float4* pw = reinterpret_cast<const float4*>(supT + (size_t)lab * CC)
                     + wv * (CHUNK / 4);

  // r9-proven inner structure: bulk loads, single fused pass
  float4 xv[JPW], wv4[JPW];
  #pragma unroll
  for (int j = 0; j < JPW; ++j) xv[j] = px[j * WAVE + lane];
  #pragma unroll
  for (int j = 0; j < JPW; ++j) wv4[j] = pw[j * WAVE + lane];

  float m = -INFINITY; int mi = 0x7fffffff;
  float se = 0.f, W = 0.f, WX = 0.f;
  #pragma unroll
  for (int j = 0; j < JPW; ++j) {
    const int base = wv * CHUNK + (j * WAVE + lane) * 4;
    amax2(xv[j].x, base + 0, m, mi);
    amax2(xv[j].y, base + 1, m, mi);
    amax2(xv[j].z, base + 2, m, mi);
    amax2(xv[j].w, base + 3, m, mi);
    se += __expf(xv[j].x) + __expf(xv[j].y) + __expf(xv[j].z) + __expf(xv[j].w);
    W  += wv4[j].x + wv4[j].y + wv4[j].z + wv4[j].w;
    WX += wv4[j].x * xv[j].x + wv4[j].y * xv[j].y
        + wv4[j].z * xv[j].z + wv4[j].w * xv[j].w;
  }
  wave_argmax(m, mi);
  se = wave_sum(se);
  W  = wave_sum(W);
  WX = wave_sum(WX);
  if (lane == 0) {
    s_m[wv] = m; s_mi[wv] = mi; s_se[wv] = se; s_W[wv] = W; s_WX[wv] = WX;
  }
  __syncthreads();

  // block reduce (all threads; block-uniform results)
  float pm = s_m[0]; int pred = s_mi[0];
  amax2(s_m[1], s_mi[1], pm, pred);
  amax2(s_m[2], s_mi[2], pm, pred);
  amax2(s_m[3], s_mi[3], pm, pred);
  const float Z   = s_se[0] + s_se[1] + s_se[2] + s_se[3];
  const float Wt  = s_W[0] + s_W[1] + s_W[2] + s_W[3];
  const float WXt = s_WX[0] + s_WX[1] + s_WX[2] + s_WX[3];
  const float logZ = __logf(Z);

  if (tid == 0) {
    const float xl = y_h[roff + lab];          // L2-hot (this block read the row)
    const int slot = (b & (ACC_SLOTS - 1)) * 2;
    atomicAdd(&acc[slot + 0], (double)(logZ - xl));        // hard
    atomicAdd(&acc[slot + 1], (double)(logZ * Wt - WXt));  // soft
    if (pred == lab) atomicAdd(&cnt[pred], 1.0f);
  }

  // rare, block-uniform: scatter probs into update column `pred`
  if (pred == lab) {
    const float invZ = 1.0f / Z;
    const float4* pr = reinterpret_cast<const float4*>(y_h + roff);
    #pragma unroll
    for (int j = 0; j < 4; ++j) {
      const int i4 = j * TPB + tid;
      const float4 q = pr[i4];                 // L2-hot re-read
      const int base = i4 * 4;
      atomicAdd(&upd[(size_t)(base + 0) * CC + pred], __expf(q.x) * invZ);
      atomicAdd(&upd[(size_t)(base + 1) * CC + pred], __expf(q.y) * invZ);
      atomicAdd(&upd[(size_t)(base + 2) * CC + pred], __expf(q.z) * invZ);
      atomicAdd(&upd[(size_t)(base + 3) * CC + pred], __expf(q.w) * invZ);
    }
  }
}

__global__ void ols_finalize(const double* __restrict__ acc,
                             float* __restrict__ out, double invB) {
  double h = 0.0, s = 0.0;
  for (int i = 0; i < ACC_SLOTS; ++i) { h += acc[i * 2]; s += acc[i * 2 + 1]; }
  out[0] = (float)(((double)ALPHA_V * h + (1.0 - (double)ALPHA_V) * s) * invB);
}

// ---- fallback (tiny ws): fused per-row kernel, direct sup column reads ----
__global__ void ols_fallback(const float* __restrict__ y_h, const float* __restrict__ y,
                             const float* __restrict__ sup,
                             float* __restrict__ upd, float* __restrict__ cnt,
                             double* __restrict__ acc) {
  const int wv = threadIdx.x >> 6, lane = threadIdx.x & 63;
  const int b = blockIdx.x * WPB + wv;
  const size_t roff = (size_t)b * CC;
  const float4* y4 = reinterpret_cast<const float4*>(y + roff);
  const float4* x4 = reinterpret_cast<const float4*>(y_h + roff);
  const int K16 = CC / (WAVE * 4);

  float lv = -INFINITY; int li = 0x7fffffff;
  for (int k = 0; k < K16; ++k) {
    const float4 v = y4[k * WAVE + lane];
    const int base = (k * WAVE + lane) * 4;
    amax2(v.x, base + 0, lv, li); amax2(v.y, base + 1, lv, li);
    amax2(v.z, base + 2, lv, li); amax2(v.w, base + 3, lv, li);
  }
  wave_argmax(lv, li);
  const int lab = li;
  const float xl = y_h[roff + lab];

  float m = -INFINITY; int mi = 0x7fffffff;
  float se = 0.f, W = 0.f, WX = 0.f;
  for (int k = 0; k < K16; ++k) {
    const float4 xv = x4[k * WAVE + lane];
    const int base = (k * WAVE + lane) * 4;
    const float w0 = sup[(size_t)(base + 0) * CC + lab];
    const float w1 = sup[(size_t)(base + 1) * CC + lab];
    const float w2 = sup[(size_t)(base + 2) * CC + lab];
    const float w3 = sup[(size_t)(base + 3) * CC + lab];
    amax2(xv.x, base + 0, m, mi); amax2(xv.y, base + 1, m, mi);
    amax2(xv.z, base + 2, m, mi); amax2(xv.w, base + 3, m, mi);
    se += __expf(xv.x) + __expf(xv.y) + __expf(xv.z) + __expf(xv.w);
    W  += w0 + w1 + w2 + w3;
    WX += w0 * xv.x + w1 * xv.y + w2 * xv.z + w3 * xv.w;
  }
  wave_argmax(m, mi);
  const int pred = mi;
  const float Z = wave_sum(se), Wt = wave_sum(W), WXt = wave_sum(WX);
  const float logZ = __logf(Z);
  if (pred == lab) {
    const float invZ = 1.0f / Z;
    for (int k = 0; k < K16; ++k) {
      const float4 xv = x4[k * WAVE + lane];
      const int base = (k * WAVE + lane) * 4;
      atomicAdd(&upd[(size_t)(base + 0) * CC + pred], __expf(xv.x) * invZ);
      atomicAdd(&upd[(size_t)(base + 1) * CC + pred], __expf(xv.y) * invZ);
      atomicAdd(&upd[(size_t)(base + 2) * CC + pred], __expf(xv.z) * invZ);
      atomicAdd(&upd[(size_t)(base + 3) * CC + pred], __expf(xv.w) * invZ);
    }
    if (lane == 0) atomicAdd(&cnt[pred], 1.0f);
  }
  if (lane == 0) {
    const int slot = (b & (ACC_SLOTS - 1)) * 2;
    atomicAdd(&acc[slot + 0], (double)(logZ - xl));
    atomicAdd(&acc[slot + 1], (double)(logZ * Wt - WXt));
  }
}

extern "C" void kernel_launch(void* const* d_in, const int* in_sizes, int n_in,
                              void* d_out, int out_size, void* d_ws, size_t ws_size,
                              hipStream_t stream) {
  const float* y_h = (const float*)d_in[0];
  const float* y   = (const float*)d_in[1];
  const float* sup = (const float*)d_in[2];
  const int C = CC;                       // 4096 (supervise is C*C)
  const int B = in_sizes[0] / C;          // 16384

  float* out        = (float*)d_out;
  float* out_update = out + 1;
  float* out_count  = out + 1 + (size_t)C * C;

  // ws layout: acc @0 (1KB) | labels @4096 (B*4=64KB) | supT @69632 (64MB)
  char* ws = (char*)d_ws;
  double* acc    = (double*)ws;
  int*    labels = (int*)(ws + 4096);
  float*  supT   = (float*)(ws + 4096 + 65536);
  const size_t need = 4096 + 65536 + (size_t)C * C * sizeof(float);

  if (ws_size >= need) {
    // even blocks: (C/32)^2 = 16384 transpose tiles; odd: 16384 rows
    ols_mega<<<32768, TPB, 0, stream>>>(sup, supT, out_update, out_count,
                                        acc, y, labels, C);
    ols_row<<<B, TPB, 0, stream>>>(y_h, labels, supT,
                                   out_update, out_count, acc);
    ols_finalize<<<1, 1, 0, stream>>>(acc, out, 1.0 / (double)B);
  } else {
    hipMemsetAsync(d_out, 0, (size_t)out_size * sizeof(float), stream);
    hipMemsetAsync(d_ws, 0, 4096, stream);
    ols_fallback<<<B / WPB, TPB, 0, stream>>>(y_h, y, sup,
                                              out_update, out_count, acc);
    ols_finalize<<<1, 1, 0, stream>>>(acc, out, 1.0 / (double)B);
  }
}